// Round 1
// baseline (144.725 us; speedup 1.0000x reference)
//
#include <hip/hip_runtime.h>

#define NEG_SLOPE 0.2f

__device__ __forceinline__ float leaky(float v) { return v > 0.f ? v : NEG_SLOPE * v; }
__device__ __forceinline__ float relu_f(float v) { return v > 0.f ? v : 0.f; }

// GATv2 over a fully-connected 3-node graph with self loops (fill_value='mean').
// x: node feats [3][14], (px,py): node positions. Writes sum over target nodes
// of relu(out) into hsum[16].
__device__ __forceinline__ void gatv2(const float (&x)[3][14],
                                      const float (&px)[3], const float (&py)[3],
                                      const float* __restrict__ Wl, const float* __restrict__ bl,
                                      const float* __restrict__ Wr, const float* __restrict__ br,
                                      const float* __restrict__ We, const float* __restrict__ att,
                                      const float* __restrict__ bias,
                                      float (&hsum)[16])
{
    // xl = x @ Wl + bl (source transform), xr = x @ Wr + br (target transform)
    float xl[3][16], xr[3][16];
#pragma unroll
    for (int j = 0; j < 3; ++j) {
#pragma unroll
        for (int c = 0; c < 16; ++c) {
            float al = bl[c];
            float ar = br[c];
#pragma unroll
            for (int k = 0; k < 14; ++k) {
                al = fmaf(x[j][k], Wl[k * 16 + c], al);
                ar = fmaf(x[j][k], Wr[k * 16 + c], ar);
            }
            xl[j][c] = al;
            xr[j][c] = ar;
        }
    }

    // Edge attrs attr[j->i] = (pos_j - pos_i, ||pos_j - pos_i||); diagonal =
    // mean of incoming non-self attrs.
    float ax[3][3], ay[3][3], ad[3][3];
#pragma unroll
    for (int j = 0; j < 3; ++j) {
#pragma unroll
        for (int i = 0; i < 3; ++i) {
            if (i == j) continue;
            float dx = px[j] - px[i];
            float dy = py[j] - py[i];
            float sq = dx * dx + dy * dy;
            float dn = sq > 0.f ? sqrtf(sq) : 0.f;
            ax[j][i] = dx; ay[j][i] = dy; ad[j][i] = dn;
        }
    }
    const int o0[3] = {1, 0, 0};
    const int o1[3] = {2, 2, 1};
#pragma unroll
    for (int i = 0; i < 3; ++i) {
        int a = o0[i], b = o1[i];
        ax[i][i] = 0.5f * (ax[a][i] + ax[b][i]);
        ay[i][i] = 0.5f * (ay[a][i] + ay[b][i]);
        ad[i][i] = 0.5f * (ad[a][i] + ad[b][i]);
    }

    // logits[j][i] = att . leaky_relu(xl[j] + xr[i] + attr[j][i] @ We)
    float lg[3][3];
#pragma unroll
    for (int j = 0; j < 3; ++j) {
#pragma unroll
        for (int i = 0; i < 3; ++i) {
            float acc = 0.f;
#pragma unroll
            for (int c = 0; c < 16; ++c) {
                float e = ax[j][i] * We[c] + ay[j][i] * We[16 + c] + ad[j][i] * We[32 + c];
                float g = xl[j][c] + xr[i][c] + e;
                acc = fmaf(leaky(g), att[c], acc);
            }
            lg[j][i] = acc;
        }
    }

    // softmax over sources j per target i; out[i] = sum_j alpha * xl[j] + bias
#pragma unroll
    for (int i = 0; i < 3; ++i) {
        float m = fmaxf(lg[0][i], fmaxf(lg[1][i], lg[2][i]));
        float e0 = __expf(lg[0][i] - m);
        float e1 = __expf(lg[1][i] - m);
        float e2 = __expf(lg[2][i] - m);
        float inv = 1.f / (e0 + e1 + e2);
        float a0 = e0 * inv, a1 = e1 * inv, a2 = e2 * inv;
#pragma unroll
        for (int c = 0; c < 16; ++c) {
            float v = fmaf(a0, xl[0][c], fmaf(a1, xl[1][c], fmaf(a2, xl[2][c], bias[c])));
            hsum[c] += relu_f(v);
        }
    }
}

__global__ __launch_bounds__(256) void scl_fused_kernel(
    const float* __restrict__ agent_pos, const float* __restrict__ agent_vel,
    const float* __restrict__ rel_lm, const float* __restrict__ other_pos,
    const float* __restrict__ lm_pos,
    const float* __restrict__ Wl, const float* __restrict__ bl,
    const float* __restrict__ Wr, const float* __restrict__ br,
    const float* __restrict__ We, const float* __restrict__ att,
    const float* __restrict__ bias,
    const float* __restrict__ W1, const float* __restrict__ b1,
    const float* __restrict__ W2, const float* __restrict__ b2,
    float* __restrict__ out, int Btot)
{
    int b = blockIdx.x * blockDim.x + threadIdx.x;
    if (b >= Btot) return;

    float h[32];

    // ---------------- agent graph -> h[0..15] ----------------
    {
        float x[3][14], px[3], py[3];
#pragma unroll
        for (int j = 0; j < 3; ++j) {
            float apx = agent_pos[b * 6 + j * 2 + 0];
            float apy = agent_pos[b * 6 + j * 2 + 1];
            px[j] = apx; py[j] = apy;
            x[j][0] = apx; x[j][1] = apy;
            x[j][2] = agent_vel[b * 6 + j * 2 + 0];
            x[j][3] = agent_vel[b * 6 + j * 2 + 1];
#pragma unroll
            for (int k = 0; k < 6; ++k) x[j][4 + k] = rel_lm[b * 18 + j * 6 + k];
#pragma unroll
            for (int k = 0; k < 4; ++k) x[j][10 + k] = other_pos[b * 12 + j * 4 + k];
        }
        float hs[16];
#pragma unroll
        for (int c = 0; c < 16; ++c) hs[c] = 0.f;
        gatv2(x, px, py, Wl, bl, Wr, br, We, att, bias, hs);
#pragma unroll
        for (int c = 0; c < 16; ++c) h[c] = hs[c];
    }

    // ---------------- objective (landmark) graph -> h[16..31] ----------------
    {
        float px[3], py[3];
#pragma unroll
        for (int m = 0; m < 3; ++m) {
            px[m] = lm_pos[b * 18 + m * 2 + 0];
            py[m] = lm_pos[b * 18 + m * 2 + 1];
        }
        float x[3][14];
        const int o0[3] = {1, 0, 0};
        const int o1[3] = {2, 2, 1};
#pragma unroll
        for (int j = 0; j < 3; ++j) {
            x[j][0] = px[j]; x[j][1] = py[j];
            x[j][2] = 0.f;   x[j][3] = 0.f;
#pragma unroll
            for (int m = 0; m < 3; ++m) {
                x[j][4 + 2 * m] = px[m] - px[j];
                x[j][5 + 2 * m] = py[m] - py[j];
            }
            int a = o0[j], c2 = o1[j];
            x[j][10] = px[a] - px[j];  x[j][11] = py[a] - py[j];
            x[j][12] = px[c2] - px[j]; x[j][13] = py[c2] - py[j];
        }
        float hs[16];
#pragma unroll
        for (int c = 0; c < 16; ++c) hs[c] = 0.f;
        gatv2(x, px, py, Wl, bl, Wr, br, We, att, bias, hs);
#pragma unroll
        for (int c = 0; c < 16; ++c) h[16 + c] = hs[c];
    }

    // ---------------- MLP: relu(h @ W1 + b1) @ W2 + b2 ----------------
    float o[32];
#pragma unroll
    for (int c = 0; c < 32; ++c) o[c] = b2[c];

    for (int hc = 0; hc < 8; ++hc) {       // 8 chunks of 16 hidden units
        float z[16];
#pragma unroll
        for (int u = 0; u < 16; ++u) z[u] = b1[hc * 16 + u];
#pragma unroll
        for (int k = 0; k < 32; ++k) {
#pragma unroll
            for (int u = 0; u < 16; ++u)
                z[u] = fmaf(h[k], W1[k * 128 + hc * 16 + u], z[u]);
        }
#pragma unroll
        for (int u = 0; u < 16; ++u) {
            float zz = relu_f(z[u]);
#pragma unroll
            for (int c = 0; c < 32; ++c)
                o[c] = fmaf(zz, W2[(hc * 16 + u) * 32 + c], o[c]);
        }
    }

    // store 32 floats (two float4-sized chunks x4)
#pragma unroll
    for (int c = 0; c < 8; ++c) {
        float4 v = make_float4(o[c * 4 + 0], o[c * 4 + 1], o[c * 4 + 2], o[c * 4 + 3]);
        reinterpret_cast<float4*>(out)[b * 8 + c] = v;
    }
}

extern "C" void kernel_launch(void* const* d_in, const int* in_sizes, int n_in,
                              void* d_out, int out_size, void* d_ws, size_t ws_size,
                              hipStream_t stream) {
    const float* agent_pos = (const float*)d_in[0];
    const float* agent_vel = (const float*)d_in[1];
    const float* rel_lm    = (const float*)d_in[2];
    const float* other_pos = (const float*)d_in[3];
    const float* lm_pos    = (const float*)d_in[4];
    const float* Wl   = (const float*)d_in[5];
    const float* bl   = (const float*)d_in[6];
    const float* Wr   = (const float*)d_in[7];
    const float* br   = (const float*)d_in[8];
    const float* We   = (const float*)d_in[9];
    const float* att  = (const float*)d_in[10];
    const float* bias = (const float*)d_in[11];
    const float* W1   = (const float*)d_in[12];
    const float* b1   = (const float*)d_in[13];
    const float* W2   = (const float*)d_in[14];
    const float* b2   = (const float*)d_in[15];
    float* out = (float*)d_out;

    int B = in_sizes[0] / 6;  // agent_pos is [B,3,2]
    int block = 256;
    int grid = (B + block - 1) / block;
    scl_fused_kernel<<<grid, block, 0, stream>>>(
        agent_pos, agent_vel, rel_lm, other_pos, lm_pos,
        Wl, bl, Wr, br, We, att, bias, W1, b1, W2, b2, out, B);
}